// Round 6
// baseline (459.522 us; speedup 1.0000x reference)
//
#include <hip/hip_runtime.h>
#include <hip/hip_fp16.h>

// Fused MHA block: y = LN(x + b_proj + softmax(QK^T/8) V W_proj), MFMA compute.
// B=4, S=2048, D=1024, H=16, Dh=64.  M = B*S = 8192.
//
// Workspace layout (needs ~72 MB; aliased):
//   [0,16M)   x_bf16 [8192][1024]     -- later reused as O bf16 [8192][1024]
//   [16,22M)  wqkvT bf16 [3072n][1024k]  (wq/wk/wv transposed, contiguous)
//   [22,24M)  wprojT bf16 [1024n][1024k]
//   [24,40M)  Q bf16 [8192][1024]  (PRE-SCALED by 0.125*log2e; n = h*64+dh)
//   [40,56M)  K bf16
//   [56,72M)  V^T f16 [b][h][dh][s]   (written transposed+f16 by QKV GEMM epilogue)
//   [24,56M)  y_pre fp32 [8192][1024]  (aliases Q,K after attention)

typedef unsigned short u16;
typedef __attribute__((ext_vector_type(8))) u16 u16x8;
typedef __attribute__((ext_vector_type(4))) u16 u16x4;
typedef __attribute__((ext_vector_type(8))) __bf16 bf16x8;
typedef __attribute__((ext_vector_type(4))) _Float16 f16x4;
typedef __attribute__((ext_vector_type(2))) _Float16 f16x2;
typedef __attribute__((ext_vector_type(2))) __fp16 hf16x2;   // cvt_pkrtz return type
typedef __attribute__((ext_vector_type(4))) float f32x4;

// Q is pre-scaled by SM_C1 so scores come out of the MFMA in log2 units:
// p~ = 2^(s_scaled) = exp(s_raw/8).  The softmax offset/scale cancels in
// O = sum(p~ v)/sum(p~), so NO fma and NO offset in the inner loop.
#define SM_C1 0.1803368801111204f   /* 0.125 * log2(e) */

static __device__ __forceinline__ u16 f2bf(float f) {
  union { float f; unsigned int u; } v; v.f = f;
  unsigned int u = v.u;
  return (u16)((u + 0x7fffu + ((u >> 16) & 1u)) >> 16);  // RNE
}
static __device__ __forceinline__ u16 f2h(float f) {
  union { _Float16 h; u16 u; } v; v.h = (_Float16)f;  // v_cvt_f16_f32, RNE
  return v.u;
}

// async global->LDS, 16B per lane; LDS dest = wave-uniform base + lane*16
static __device__ __forceinline__ void gld16(const u16* g, u16* l) {
  __builtin_amdgcn_global_load_lds((const __attribute__((address_space(1))) void*)g,
                                   (__attribute__((address_space(3))) void*)l, 16, 0, 0);
}

// ---------------- conversion kernels ----------------

__global__ __launch_bounds__(256) void k_convx(const float* __restrict__ x,
                                               u16* __restrict__ xbf) {
  int i = (blockIdx.x * 256 + threadIdx.x) * 8;
  float4 a = *(const float4*)(x + i);
  float4 b = *(const float4*)(x + i + 4);
  u16x8 o;
  o[0] = f2bf(a.x); o[1] = f2bf(a.y); o[2] = f2bf(a.z); o[3] = f2bf(a.w);
  o[4] = f2bf(b.x); o[5] = f2bf(b.y); o[6] = f2bf(b.z); o[7] = f2bf(b.w);
  *(u16x8*)(xbf + i) = o;
}

// transpose 1024x1024 fp32 -> bf16 [n][k], LDS tiled, both sides coalesced
__global__ __launch_bounds__(256) void k_convwT(const float* __restrict__ w0,
                                                const float* __restrict__ w1,
                                                const float* __restrict__ w2,
                                                const float* __restrict__ w3,
                                                u16* __restrict__ o0, u16* __restrict__ o1,
                                                u16* __restrict__ o2, u16* __restrict__ o3) {
  __shared__ float tile[64][65];
  const float* w = blockIdx.z == 0 ? w0 : blockIdx.z == 1 ? w1 : blockIdx.z == 2 ? w2 : w3;
  u16* o = blockIdx.z == 0 ? o0 : blockIdx.z == 1 ? o1 : blockIdx.z == 2 ? o2 : o3;
  const int k0 = blockIdx.x * 64, n0 = blockIdx.y * 64;
  const int t = threadIdx.x;
#pragma unroll
  for (int i = 0; i < 16; i++) {
    int idx = t + 256 * i;
    int k = idx >> 6, n = idx & 63;
    tile[k][n] = w[(k0 + k) * 1024 + n0 + n];
  }
  __syncthreads();
#pragma unroll
  for (int i = 0; i < 16; i++) {
    int idx = t + 256 * i;
    int n = idx >> 6, k = idx & 63;
    o[(n0 + n) * 1024 + k0 + k] = f2bf(tile[k][n]);
  }
}

// ---------------- QKV GEMM (m97 structure) ----------------
// 128x128 tile, BK=64, 4 waves as 2x2, 4x4 16x16x32 frags/wave.
// Staging via global_load_lds dwordx4; XOR-swizzled granules (kg = pg ^ (row&7))
// so ds_read_b128 fragment reads are bank-conflict-free without padding.
// wT is the fused [3072][1024] (wq|wk|wv transposed). sel: 0 -> Q bf16*SM_C1;
// 1 -> K bf16 row-major; 2 -> V^T f16 [b][h][dh][s].

__global__ __launch_bounds__(256) void k_gemm_qkv(const u16* __restrict__ xbf,
                                                  const u16* __restrict__ wT,
                                                  u16* __restrict__ Qb, u16* __restrict__ Kb,
                                                  u16* __restrict__ VbT) {
  __shared__ alignas(16) u16 Als[128 * 64];
  __shared__ alignas(16) u16 Bls[128 * 64];
  const int t = threadIdx.x;
  const int wv = t >> 6, lane = t & 63, quad = lane >> 4, l16 = lane & 15;
  const int wm = wv >> 1, wn = wv & 1;
  const int m0 = blockIdx.x * 128;
  const int nt = blockIdx.y;                 // 0..23
  const int row = t >> 3;                    // staging row 0..31 (+32 per issue)
  const int kg = (t & 7) ^ (row & 7);        // swizzled k-granule
  const u16* aG = xbf + (size_t)(m0 + row) * 1024 + kg * 8;
  const u16* bG = wT + (size_t)(nt * 128 + row) * 1024 + kg * 8;
  const int sw = l16 & 7;
  const int aA0 = (wm * 64 + l16) * 64 + ((quad) ^ sw) * 8;
  const int aA1 = (wm * 64 + l16) * 64 + ((4 + quad) ^ sw) * 8;
  const int bA0 = (wn * 64 + l16) * 64 + ((quad) ^ sw) * 8;
  const int bA1 = (wn * 64 + l16) * 64 + ((4 + quad) ^ sw) * 8;

  f32x4 acc[4][4] = {};
  for (int k0 = 0; k0 < 1024; k0 += 64) {
    __syncthreads();
#pragma unroll
    for (int i = 0; i < 4; i++) {
      gld16(aG + i * 32 * 1024 + k0, &Als[(i * 256 + wv * 64) * 8]);
      gld16(bG + i * 32 * 1024 + k0, &Bls[(i * 256 + wv * 64) * 8]);
    }
    __syncthreads();
#pragma unroll
    for (int c = 0; c < 2; c++) {
      bf16x8 a[4], b[4];
#pragma unroll
      for (int f = 0; f < 4; f++) a[f] = *(const bf16x8*)&Als[(c ? aA1 : aA0) + f * 1024];
#pragma unroll
      for (int g = 0; g < 4; g++) b[g] = *(const bf16x8*)&Bls[(c ? bA1 : bA0) + g * 1024];
#pragma unroll
      for (int f = 0; f < 4; f++)
#pragma unroll
        for (int g = 0; g < 4; g++)
          acc[f][g] = __builtin_amdgcn_mfma_f32_16x16x32_bf16(a[f], b[g], acc[f][g], 0, 0, 0);
    }
  }

  const int sel = nt >> 3;
  const int n0 = (nt & 7) * 128 + wn * 64;
  const int mBase = m0 + wm * 64 + quad * 4;
  if (sel < 2) {
    u16* Ob = sel == 0 ? Qb : Kb;
    const float scl = sel == 0 ? SM_C1 : 1.0f;
#pragma unroll
    for (int f = 0; f < 4; f++)
#pragma unroll
      for (int g = 0; g < 4; g++)
#pragma unroll
        for (int r = 0; r < 4; r++) {
          int m = mBase + f * 16 + r;
          int n = n0 + g * 16 + l16;
          Ob[(size_t)m * 1024 + n] = f2bf(acc[f][g][r] * scl);
        }
  } else {
    // V^T f16: [b][h][dh][s]; 4 r-values are 4 consecutive s -> one 8B store
#pragma unroll
    for (int f = 0; f < 4; f++) {
      int m = mBase + f * 16;
      int bb = m >> 11, s = m & 2047;
#pragma unroll
      for (int g = 0; g < 4; g++) {
        int n = n0 + g * 16 + l16;
        int hh = n >> 6, dh = n & 63;
        u16x4 o;
#pragma unroll
        for (int r = 0; r < 4; r++) o[r] = f2h(acc[f][g][r]);
        *(u16x4*)&VbT[(size_t)(((bb << 4) + hh) * 64 + dh) * 2048 + s] = o;
      }
    }
  }
}

// ---------------- proj GEMM + bias + residual (same m97 structure) ----------------

__global__ __launch_bounds__(256) void k_gemm_proj(const u16* __restrict__ Abf,
                                                   const u16* __restrict__ wT,
                                                   const float* __restrict__ x,
                                                   const float* __restrict__ bias,
                                                   float* __restrict__ ypre) {
  __shared__ alignas(16) u16 Als[128 * 64];
  __shared__ alignas(16) u16 Bls[128 * 64];
  const int t = threadIdx.x;
  const int wv = t >> 6, lane = t & 63, quad = lane >> 4, l16 = lane & 15;
  const int wm = wv >> 1, wn = wv & 1;
  const int m0 = blockIdx.x * 128;
  const int n0t = blockIdx.y * 128;
  const int row = t >> 3;
  const int kg = (t & 7) ^ (row & 7);
  const u16* aG = Abf + (size_t)(m0 + row) * 1024 + kg * 8;
  const u16* bG = wT + (size_t)(n0t + row) * 1024 + kg * 8;
  const int sw = l16 & 7;
  const int aA0 = (wm * 64 + l16) * 64 + ((quad) ^ sw) * 8;
  const int aA1 = (wm * 64 + l16) * 64 + ((4 + quad) ^ sw) * 8;
  const int bA0 = (wn * 64 + l16) * 64 + ((quad) ^ sw) * 8;
  const int bA1 = (wn * 64 + l16) * 64 + ((4 + quad) ^ sw) * 8;

  f32x4 acc[4][4] = {};
  for (int k0 = 0; k0 < 1024; k0 += 64) {
    __syncthreads();
#pragma unroll
    for (int i = 0; i < 4; i++) {
      gld16(aG + i * 32 * 1024 + k0, &Als[(i * 256 + wv * 64) * 8]);
      gld16(bG + i * 32 * 1024 + k0, &Bls[(i * 256 + wv * 64) * 8]);
    }
    __syncthreads();
#pragma unroll
    for (int c = 0; c < 2; c++) {
      bf16x8 a[4], b[4];
#pragma unroll
      for (int f = 0; f < 4; f++) a[f] = *(const bf16x8*)&Als[(c ? aA1 : aA0) + f * 1024];
#pragma unroll
      for (int g = 0; g < 4; g++) b[g] = *(const bf16x8*)&Bls[(c ? bA1 : bA0) + g * 1024];
#pragma unroll
      for (int f = 0; f < 4; f++)
#pragma unroll
        for (int g = 0; g < 4; g++)
          acc[f][g] = __builtin_amdgcn_mfma_f32_16x16x32_bf16(a[f], b[g], acc[f][g], 0, 0, 0);
    }
  }

  const int n0 = n0t + wn * 64;
  const int mBase = m0 + wm * 64 + quad * 4;
#pragma unroll
  for (int g = 0; g < 4; g++) {
    int n = n0 + g * 16 + l16;
    float bn = bias[n];
#pragma unroll
    for (int f = 0; f < 4; f++)
#pragma unroll
      for (int r = 0; r < 4; r++) {
        int m = mBase + f * 16 + r;
        ypre[(size_t)m * 1024 + n] = acc[f][g][r] + bn + x[(size_t)m * 1024 + n];
      }
  }
}

// ---------------- flash attention (transposed-score, V-direct) ----------------
// grid (S/128, B*H); block 256 = 4 waves; wave handles 32 q (2 q-frags).
// S^T = K Q_scaled^T via 16x16x32 bf16 MFMA (C-layout: col=q, row=kv).
// p~ = 2^(s) computed with packed f16 (no offset/fma: scale folded into Q,
// normalization cancels the rest).  P^T (C-layout) == B-operand layout of
// 16x16x16 f16 MFMA; V^T[b][h][dh][s] in HBM == A-operand layout -> PV needs
// NO LDS at all.  Only K is LDS-staged (double-buffered, 1 barrier/iter).

__global__ __launch_bounds__(256) void k_attn(const u16* __restrict__ Qb,
                                              const u16* __restrict__ Kb,
                                              const u16* __restrict__ VbT,
                                              u16* __restrict__ Ob) {
  __shared__ alignas(16) u16 Kls[2][64 * 72];   // [kv][dh] bf16
  const int b = blockIdx.y >> 4, h = blockIdx.y & 15;
  const int q0 = blockIdx.x * 128;
  const int t = threadIdx.x;
  const int wave = t >> 6, lane = t & 63, quad = lane >> 4, l16 = lane & 15;
  const int sr = t >> 2, sc = (t & 3) * 8;

  // Q fragments (pre-scaled): per-lane data identical for A-of-QK^T / B-of-KQ^T
  bf16x8 aq[2][2];
#pragma unroll
  for (int qf = 0; qf < 2; qf++)
#pragma unroll
    for (int c = 0; c < 2; c++)
      aq[qf][c] = *(const bf16x8*)&Qb[(size_t)(b * 2048 + q0 + wave * 32 + qf * 16 + l16) * 1024 +
                                      h * 64 + c * 32 + quad * 8];

  f32x4 Oacc[2][4] = {};   // [qf][dh-frag g]; C-layout col=q, row=dh_local
  float psum[2] = {};      // per-lane partial row sum for q=l16 (per qf)

  const u16* kBase = Kb + (size_t)(b * 2048) * 1024 + h * 64;
  const u16* vtBase = VbT + (size_t)((b * 16 + h) * 64) * 2048;

  u16x8 rk0, rk1;
  {
    const u16* kR = kBase + (size_t)sr * 1024;
    rk0 = *(const u16x8*)(kR + sc);
    rk1 = *(const u16x8*)(kR + sc + 32);
  }

  for (int kt = 0; kt < 32; kt++) {
    const int p = kt & 1;
    const int kv0 = kt * 64;
    // stage K regs -> LDS[p]
    *(u16x8*)&Kls[p][sr * 72 + sc]      = rk0;
    *(u16x8*)&Kls[p][sr * 72 + sc + 32] = rk1;
    __syncthreads();

    // V A-operand frags straight from global (one 128B line per dh row,
    // L1/L2-resident; issued early so QK+softmax hides the latency)
    f16x4 va[4][4];  // [f=kv16-frag][g=dh-frag]
#pragma unroll
    for (int f = 0; f < 4; f++)
#pragma unroll
      for (int g = 0; g < 4; g++)
        va[f][g] = *(const f16x4*)&vtBase[(size_t)(g * 16 + l16) * 2048 + kv0 + f * 16 + quad * 4];

    // prefetch K kt+1
    if (kt < 31) {
      const u16* kR = kBase + (size_t)(kv0 + 64 + sr) * 1024;
      rk0 = *(const u16x8*)(kR + sc);
      rk1 = *(const u16x8*)(kR + sc + 32);
    }

    // S^T = K Q^T : A = K-frag (m=kv), B = Q-frag (n=q)
    f32x4 st[2][4] = {};   // [qf][kv-frag f]
#pragma unroll
    for (int c = 0; c < 2; c++) {
      bf16x8 bk[4];
#pragma unroll
      for (int f = 0; f < 4; f++)
        bk[f] = *(const bf16x8*)&Kls[p][(f * 16 + l16) * 72 + c * 32 + quad * 8];
#pragma unroll
      for (int qf = 0; qf < 2; qf++)
#pragma unroll
        for (int f = 0; f < 4; f++)
          st[qf][f] = __builtin_amdgcn_mfma_f32_16x16x32_bf16(bk[f], aq[qf][c], st[qf][f], 0, 0, 0);
    }

    // p~ = 2^s, packed f16; accumulate row sums; feed PV directly from regs
#pragma unroll
    for (int qf = 0; qf < 2; qf++) {
      union PK { hf16x2 r; f16x2 v; __half2 h; };
      PK e01[4], e23[4];
      __half2 it2 = __half2{__half(0.f), __half(0.f)};
#pragma unroll
      for (int f = 0; f < 4; f++) {
        PK a01, a23;
        a01.r = __builtin_amdgcn_cvt_pkrtz(st[qf][f][0], st[qf][f][1]);
        a23.r = __builtin_amdgcn_cvt_pkrtz(st[qf][f][2], st[qf][f][3]);
        e01[f].h = h2exp2(a01.h);
        e23[f].h = h2exp2(a23.h);
        it2 = __hadd2(it2, __hadd2(e01[f].h, e23[f].h));
      }
      psum[qf] += __low2float(it2) + __high2float(it2);
      // O^T += V^T P^T : A = va (from HBM), B = P^T frag (from regs)
#pragma unroll
      for (int f = 0; f < 4; f++) {
        union { f16x4 v; f16x2 h[2]; } pb;
        pb.h[0] = e01[f].v;
        pb.h[1] = e23[f].v;
#pragma unroll
        for (int g = 0; g < 4; g++)
          Oacc[qf][g] = __builtin_amdgcn_mfma_f32_16x16x16f16(va[f][g], pb.v, Oacc[qf][g], 0, 0, 0);
      }
    }
  }

  // psum: lanes with same l16 across the 4 quads hold disjoint kv subsets
  float inv[2];
#pragma unroll
  for (int qf = 0; qf < 2; qf++) {
    float v = psum[qf];
    v += __shfl_xor(v, 16);
    v += __shfl_xor(v, 32);
    inv[qf] = 1.f / v;
  }

  // epilogue: O^T (col=q, row=dh) -> LDS transpose -> coalesced row-major store
  __syncthreads();
  u16* Ols = (u16*)Kls;  // 128 rows x 72 pitch = 9216 u16 (fits in Kls)
#pragma unroll
  for (int qf = 0; qf < 2; qf++)
#pragma unroll
    for (int g = 0; g < 4; g++) {
      u16x4 o;
#pragma unroll
      for (int r = 0; r < 4; r++) o[r] = f2bf(Oacc[qf][g][r] * inv[qf]);
      *(u16x4*)&Ols[(wave * 32 + qf * 16 + l16) * 72 + g * 16 + quad * 4] = o;
    }
  __syncthreads();
  const int row = t >> 1, half = t & 1;
  u16* gO = Ob + (size_t)(b * 2048 + q0 + row) * 1024 + h * 64 + half * 32;
#pragma unroll
  for (int j = 0; j < 4; j++)
    *(u16x8*)(gO + j * 8) = *(const u16x8*)&Ols[row * 72 + half * 32 + j * 8];
}

// ---------------- LayerNorm ----------------

__global__ __launch_bounds__(256) void k_ln(const float* __restrict__ y,
                                            const float* __restrict__ g,
                                            const float* __restrict__ bt,
                                            float* __restrict__ out) {
  const int row = blockIdx.x;
  const int t = threadIdx.x;
  float4 v = *(const float4*)(y + row * 1024 + t * 4);
  float s1 = v.x + v.y + v.z + v.w;
  float s2 = v.x * v.x + v.y * v.y + v.z * v.z + v.w * v.w;
#pragma unroll
  for (int off = 32; off; off >>= 1) {
    s1 += __shfl_down(s1, off);
    s2 += __shfl_down(s2, off);
  }
  __shared__ float red[10];
  const int wave = t >> 6, lane = t & 63;
  if (lane == 0) { red[wave] = s1; red[4 + wave] = s2; }
  __syncthreads();
  if (t == 0) {
    float a = red[0] + red[1] + red[2] + red[3];
    float bsum = red[4] + red[5] + red[6] + red[7];
    float mean = a * (1.f / 1024.f);
    float var = bsum * (1.f / 1024.f) - mean * mean;
    red[8] = mean;
    red[9] = rsqrtf(var + 1e-6f);
  }
  __syncthreads();
  float mean = red[8], iv = red[9];
  float4 gv = *(const float4*)(g + t * 4);
  float4 bv = *(const float4*)(bt + t * 4);
  float4 o;
  o.x = (v.x - mean) * iv * gv.x + bv.x;
  o.y = (v.y - mean) * iv * gv.y + bv.y;
  o.z = (v.z - mean) * iv * gv.z + bv.z;
  o.w = (v.w - mean) * iv * gv.w + bv.w;
  *(float4*)(out + row * 1024 + t * 4) = o;
}

// ---------------- launch ----------------

extern "C" void kernel_launch(void* const* d_in, const int* in_sizes, int n_in,
                              void* d_out, int out_size, void* d_ws, size_t ws_size,
                              hipStream_t stream) {
  const float* x  = (const float*)d_in[0];
  const float* wq = (const float*)d_in[1];
  const float* wk = (const float*)d_in[2];
  const float* wv = (const float*)d_in[3];
  const float* wp = (const float*)d_in[4];
  const float* bp = (const float*)d_in[5];
  const float* g  = (const float*)d_in[6];
  const float* bt = (const float*)d_in[7];
  float* out = (float*)d_out;
  char* ws = (char*)d_ws;

  u16* xbf = (u16*)(ws);
  u16* wqT = (u16*)(ws + (16 << 20));        // [3072][1024] fused: wq|wk|wv
  u16* wkT = wqT + (size_t)1024 * 1024;
  u16* wvT = wqT + (size_t)2048 * 1024;
  u16* wpT = (u16*)(ws + (22 << 20));
  u16* Qb  = (u16*)(ws + (24 << 20));
  u16* Kb  = (u16*)(ws + (40 << 20));
  u16* VbT = (u16*)(ws + (56 << 20));
  u16* Ob  = (u16*)(ws);                   // aliases xbf (dead after QKV GEMM)
  float* ypre = (float*)(ws + (24 << 20)); // aliases Q,K (dead after attention)

  k_convx<<<4096, 256, 0, stream>>>(x, xbf);
  k_convwT<<<dim3(16, 16, 4), 256, 0, stream>>>(wq, wk, wv, wp, wqT, wkT, wvT, wpT);
  k_gemm_qkv<<<dim3(64, 24), 256, 0, stream>>>(xbf, wqT, Qb, Kb, VbT);
  k_attn<<<dim3(16, 64), 256, 0, stream>>>(Qb, Kb, VbT, Ob);
  k_gemm_proj<<<dim3(64, 8), 256, 0, stream>>>(Ob, wpT, x, bp, ypre);
  k_ln<<<8192, 256, 0, stream>>>(ypre, g, bt, out);
}

// Round 7
// 305.105 us; speedup vs baseline: 1.5061x; 1.5061x over previous
//
#include <hip/hip_runtime.h>
#include <hip/hip_fp16.h>

// Fused MHA block: y = LN(x + b_proj + softmax(QK^T/8) V W_proj), MFMA compute.
// B=4, S=2048, D=1024, H=16, Dh=64.  M = B*S = 8192.
//
// Workspace layout (needs ~72 MB; aliased):
//   [0,16M)   x_bf16 [8192][1024]     -- later reused as O bf16 [8192][1024]
//   [16,22M)  wqkvT bf16 [3072n][1024k]  (wq/wk/wv transposed, contiguous)
//   [22,24M)  wprojT bf16 [1024n][1024k]
//   [24,40M)  Q bf16 [8192][1024]  (PRE-SCALED by 0.125*log2e; n = h*64+dh)
//   [40,56M)  K bf16
//   [56,72M)  V^T f16 [b][h][dh][s]   (written transposed+f16 by QKV GEMM epilogue)
//   [24,56M)  y_pre fp32 [8192][1024]  (aliases Q,K after attention)

typedef unsigned short u16;
typedef __attribute__((ext_vector_type(8))) u16 u16x8;
typedef __attribute__((ext_vector_type(4))) u16 u16x4;
typedef __attribute__((ext_vector_type(8))) __bf16 bf16x8;
typedef __attribute__((ext_vector_type(4))) _Float16 f16x4;
typedef __attribute__((ext_vector_type(2))) _Float16 f16x2;
typedef __attribute__((ext_vector_type(2))) __fp16 hf16x2;   // cvt_pkrtz return type
typedef __attribute__((ext_vector_type(4))) float f32x4;

// Q is pre-scaled by SM_C1 so scores come out of the MFMA in log2 units:
// p~ = 2^(s_scaled) = exp(s_raw/8).  The softmax offset/scale cancels in
// O = sum(p~ v)/sum(p~), so NO fma and NO offset in the inner loop.
#define SM_C1 0.1803368801111204f   /* 0.125 * log2(e) */

static __device__ __forceinline__ u16 f2bf(float f) {
  union { float f; unsigned int u; } v; v.f = f;
  unsigned int u = v.u;
  return (u16)((u + 0x7fffu + ((u >> 16) & 1u)) >> 16);  // RNE
}
static __device__ __forceinline__ u16 f2h(float f) {
  union { _Float16 h; u16 u; } v; v.h = (_Float16)f;  // v_cvt_f16_f32, RNE
  return v.u;
}

// async global->LDS, 16B per lane; LDS dest = wave-uniform base + lane*16
static __device__ __forceinline__ void gld16(const u16* g, u16* l) {
  __builtin_amdgcn_global_load_lds((const __attribute__((address_space(1))) void*)g,
                                   (__attribute__((address_space(3))) void*)l, 16, 0, 0);
}

// ---------------- conversion kernels ----------------

__global__ __launch_bounds__(256) void k_convx(const float* __restrict__ x,
                                               u16* __restrict__ xbf) {
  int i = (blockIdx.x * 256 + threadIdx.x) * 8;
  float4 a = *(const float4*)(x + i);
  float4 b = *(const float4*)(x + i + 4);
  u16x8 o;
  o[0] = f2bf(a.x); o[1] = f2bf(a.y); o[2] = f2bf(a.z); o[3] = f2bf(a.w);
  o[4] = f2bf(b.x); o[5] = f2bf(b.y); o[6] = f2bf(b.z); o[7] = f2bf(b.w);
  *(u16x8*)(xbf + i) = o;
}

// transpose 1024x1024 fp32 -> bf16 [n][k], LDS tiled, both sides coalesced
__global__ __launch_bounds__(256) void k_convwT(const float* __restrict__ w0,
                                                const float* __restrict__ w1,
                                                const float* __restrict__ w2,
                                                const float* __restrict__ w3,
                                                u16* __restrict__ o0, u16* __restrict__ o1,
                                                u16* __restrict__ o2, u16* __restrict__ o3) {
  __shared__ float tile[64][65];
  const float* w = blockIdx.z == 0 ? w0 : blockIdx.z == 1 ? w1 : blockIdx.z == 2 ? w2 : w3;
  u16* o = blockIdx.z == 0 ? o0 : blockIdx.z == 1 ? o1 : blockIdx.z == 2 ? o2 : o3;
  const int k0 = blockIdx.x * 64, n0 = blockIdx.y * 64;
  const int t = threadIdx.x;
#pragma unroll
  for (int i = 0; i < 16; i++) {
    int idx = t + 256 * i;
    int k = idx >> 6, n = idx & 63;
    tile[k][n] = w[(k0 + k) * 1024 + n0 + n];
  }
  __syncthreads();
#pragma unroll
  for (int i = 0; i < 16; i++) {
    int idx = t + 256 * i;
    int n = idx >> 6, k = idx & 63;
    o[(n0 + n) * 1024 + k0 + k] = f2bf(tile[k][n]);
  }
}

// ---------------- QKV GEMM (m97 structure) ----------------
// 128x128 tile, BK=64, 4 waves as 2x2, 4x4 16x16x32 frags/wave.
// Staging via global_load_lds dwordx4; XOR-swizzled granules (kg = pg ^ (row&7))
// so ds_read_b128 fragment reads are bank-conflict-free without padding.
// wT is the fused [3072][1024] (wq|wk|wv transposed). sel: 0 -> Q bf16*SM_C1;
// 1 -> K bf16 row-major; 2 -> V^T f16 [b][h][dh][s].

__global__ __launch_bounds__(256) void k_gemm_qkv(const u16* __restrict__ xbf,
                                                  const u16* __restrict__ wT,
                                                  u16* __restrict__ Qb, u16* __restrict__ Kb,
                                                  u16* __restrict__ VbT) {
  __shared__ alignas(16) u16 Als[128 * 64];
  __shared__ alignas(16) u16 Bls[128 * 64];
  const int t = threadIdx.x;
  const int wv = t >> 6, lane = t & 63, quad = lane >> 4, l16 = lane & 15;
  const int wm = wv >> 1, wn = wv & 1;
  const int m0 = blockIdx.x * 128;
  const int nt = blockIdx.y;                 // 0..23
  const int row = t >> 3;                    // staging row 0..31 (+32 per issue)
  const int kg = (t & 7) ^ (row & 7);        // swizzled k-granule
  const u16* aG = xbf + (size_t)(m0 + row) * 1024 + kg * 8;
  const u16* bG = wT + (size_t)(nt * 128 + row) * 1024 + kg * 8;
  const int sw = l16 & 7;
  const int aA0 = (wm * 64 + l16) * 64 + ((quad) ^ sw) * 8;
  const int aA1 = (wm * 64 + l16) * 64 + ((4 + quad) ^ sw) * 8;
  const int bA0 = (wn * 64 + l16) * 64 + ((quad) ^ sw) * 8;
  const int bA1 = (wn * 64 + l16) * 64 + ((4 + quad) ^ sw) * 8;

  f32x4 acc[4][4] = {};
  for (int k0 = 0; k0 < 1024; k0 += 64) {
    __syncthreads();
#pragma unroll
    for (int i = 0; i < 4; i++) {
      gld16(aG + i * 32 * 1024 + k0, &Als[(i * 256 + wv * 64) * 8]);
      gld16(bG + i * 32 * 1024 + k0, &Bls[(i * 256 + wv * 64) * 8]);
    }
    __syncthreads();
#pragma unroll
    for (int c = 0; c < 2; c++) {
      bf16x8 a[4], b[4];
#pragma unroll
      for (int f = 0; f < 4; f++) a[f] = *(const bf16x8*)&Als[(c ? aA1 : aA0) + f * 1024];
#pragma unroll
      for (int g = 0; g < 4; g++) b[g] = *(const bf16x8*)&Bls[(c ? bA1 : bA0) + g * 1024];
#pragma unroll
      for (int f = 0; f < 4; f++)
#pragma unroll
        for (int g = 0; g < 4; g++)
          acc[f][g] = __builtin_amdgcn_mfma_f32_16x16x32_bf16(a[f], b[g], acc[f][g], 0, 0, 0);
    }
  }

  const int sel = nt >> 3;
  const int n0 = (nt & 7) * 128 + wn * 64;
  const int mBase = m0 + wm * 64 + quad * 4;
  if (sel < 2) {
    u16* Ob = sel == 0 ? Qb : Kb;
    const float scl = sel == 0 ? SM_C1 : 1.0f;
#pragma unroll
    for (int f = 0; f < 4; f++)
#pragma unroll
      for (int g = 0; g < 4; g++)
#pragma unroll
        for (int r = 0; r < 4; r++) {
          int m = mBase + f * 16 + r;
          int n = n0 + g * 16 + l16;
          Ob[(size_t)m * 1024 + n] = f2bf(acc[f][g][r] * scl);
        }
  } else {
    // V^T f16: [b][h][dh][s]; 4 r-values are 4 consecutive s -> one 8B store
#pragma unroll
    for (int f = 0; f < 4; f++) {
      int m = mBase + f * 16;
      int bb = m >> 11, s = m & 2047;
#pragma unroll
      for (int g = 0; g < 4; g++) {
        int n = n0 + g * 16 + l16;
        int hh = n >> 6, dh = n & 63;
        u16x4 o;
#pragma unroll
        for (int r = 0; r < 4; r++) o[r] = f2h(acc[f][g][r]);
        *(u16x4*)&VbT[(size_t)(((bb << 4) + hh) * 64 + dh) * 2048 + s] = o;
      }
    }
  }
}

// ---------------- proj GEMM + bias + residual (same m97 structure) ----------------

__global__ __launch_bounds__(256) void k_gemm_proj(const u16* __restrict__ Abf,
                                                   const u16* __restrict__ wT,
                                                   const float* __restrict__ x,
                                                   const float* __restrict__ bias,
                                                   float* __restrict__ ypre) {
  __shared__ alignas(16) u16 Als[128 * 64];
  __shared__ alignas(16) u16 Bls[128 * 64];
  const int t = threadIdx.x;
  const int wv = t >> 6, lane = t & 63, quad = lane >> 4, l16 = lane & 15;
  const int wm = wv >> 1, wn = wv & 1;
  const int m0 = blockIdx.x * 128;
  const int n0t = blockIdx.y * 128;
  const int row = t >> 3;
  const int kg = (t & 7) ^ (row & 7);
  const u16* aG = Abf + (size_t)(m0 + row) * 1024 + kg * 8;
  const u16* bG = wT + (size_t)(n0t + row) * 1024 + kg * 8;
  const int sw = l16 & 7;
  const int aA0 = (wm * 64 + l16) * 64 + ((quad) ^ sw) * 8;
  const int aA1 = (wm * 64 + l16) * 64 + ((4 + quad) ^ sw) * 8;
  const int bA0 = (wn * 64 + l16) * 64 + ((quad) ^ sw) * 8;
  const int bA1 = (wn * 64 + l16) * 64 + ((4 + quad) ^ sw) * 8;

  f32x4 acc[4][4] = {};
  for (int k0 = 0; k0 < 1024; k0 += 64) {
    __syncthreads();
#pragma unroll
    for (int i = 0; i < 4; i++) {
      gld16(aG + i * 32 * 1024 + k0, &Als[(i * 256 + wv * 64) * 8]);
      gld16(bG + i * 32 * 1024 + k0, &Bls[(i * 256 + wv * 64) * 8]);
    }
    __syncthreads();
#pragma unroll
    for (int c = 0; c < 2; c++) {
      bf16x8 a[4], b[4];
#pragma unroll
      for (int f = 0; f < 4; f++) a[f] = *(const bf16x8*)&Als[(c ? aA1 : aA0) + f * 1024];
#pragma unroll
      for (int g = 0; g < 4; g++) b[g] = *(const bf16x8*)&Bls[(c ? bA1 : bA0) + g * 1024];
#pragma unroll
      for (int f = 0; f < 4; f++)
#pragma unroll
        for (int g = 0; g < 4; g++)
          acc[f][g] = __builtin_amdgcn_mfma_f32_16x16x32_bf16(a[f], b[g], acc[f][g], 0, 0, 0);
    }
  }

  const int n0 = n0t + wn * 64;
  const int mBase = m0 + wm * 64 + quad * 4;
#pragma unroll
  for (int g = 0; g < 4; g++) {
    int n = n0 + g * 16 + l16;
    float bn = bias[n];
#pragma unroll
    for (int f = 0; f < 4; f++)
#pragma unroll
      for (int r = 0; r < 4; r++) {
        int m = mBase + f * 16 + r;
        ypre[(size_t)m * 1024 + n] = acc[f][g][r] + bn + x[(size_t)m * 1024 + n];
      }
  }
}

// ---------------- flash attention (transposed-score form) ----------------
// grid (S/128, B*H); block 256 = 4 waves; wave handles 32 q (2 q-frags).
// S^T = K Q_scaled^T via 16x16x32 bf16 MFMA (C-layout: col=q, row=kv).
// p~ = 2^s via packed-f16 exp (scale folded into Q; offset cancels in the
// normalization).  P^T (C-layout) == B-operand layout of 16x16x16 f16 MFMA
// -> PV feeds straight from registers.  K and V^T staged in LDS (coalesced,
// double-buffered, 1 barrier/iter) -- V-from-HBM gather was a latency
// disaster (R5: 16 lines/instr, 279us), LDS staging is the proven path.

__global__ __launch_bounds__(256) void k_attn(const u16* __restrict__ Qb,
                                              const u16* __restrict__ Kb,
                                              const u16* __restrict__ VbT,
                                              u16* __restrict__ Ob) {
  __shared__ alignas(16) u16 Kls[2][64 * 72];   // [kv][dh] bf16
  __shared__ alignas(16) u16 Vls[2][64 * 72];   // [dh][kv] f16
  const int b = blockIdx.y >> 4, h = blockIdx.y & 15;
  const int q0 = blockIdx.x * 128;
  const int t = threadIdx.x;
  const int wave = t >> 6, lane = t & 63, quad = lane >> 4, l16 = lane & 15;
  const int sr = t >> 2, sc = (t & 3) * 8;

  // Q fragments (pre-scaled): per-lane data identical for A-of-QK^T / B-of-KQ^T
  bf16x8 aq[2][2];
#pragma unroll
  for (int qf = 0; qf < 2; qf++)
#pragma unroll
    for (int c = 0; c < 2; c++)
      aq[qf][c] = *(const bf16x8*)&Qb[(size_t)(b * 2048 + q0 + wave * 32 + qf * 16 + l16) * 1024 +
                                      h * 64 + c * 32 + quad * 8];

  f32x4 Oacc[2][4] = {};   // [qf][dh-frag g]; C-layout col=q, row=dh_local
  float psum[2] = {};      // per-lane partial row sum for q=l16 (per qf)

  const u16* kBase = Kb + (size_t)(b * 2048) * 1024 + h * 64;
  const u16* vtRow = VbT + (size_t)((b * 16 + h) * 64 + sr) * 2048;

  u16x8 rk0, rk1, rv0, rv1;
  {
    const u16* kR = kBase + (size_t)sr * 1024;
    rk0 = *(const u16x8*)(kR + sc);
    rk1 = *(const u16x8*)(kR + sc + 32);
    rv0 = *(const u16x8*)(vtRow + sc);
    rv1 = *(const u16x8*)(vtRow + sc + 32);
  }

  for (int kt = 0; kt < 32; kt++) {
    const int p = kt & 1;
    // stage regs -> LDS[p]
    *(u16x8*)&Kls[p][sr * 72 + sc]      = rk0;
    *(u16x8*)&Kls[p][sr * 72 + sc + 32] = rk1;
    *(u16x8*)&Vls[p][sr * 72 + sc]      = rv0;
    *(u16x8*)&Vls[p][sr * 72 + sc + 32] = rv1;
    __syncthreads();
    // prefetch kt+1 (consumed at next iter's write; hidden under compute)
    if (kt < 31) {
      const int kv1 = (kt + 1) * 64;
      const u16* kR = kBase + (size_t)(kv1 + sr) * 1024;
      rk0 = *(const u16x8*)(kR + sc);
      rk1 = *(const u16x8*)(kR + sc + 32);
      rv0 = *(const u16x8*)(vtRow + kv1 + sc);
      rv1 = *(const u16x8*)(vtRow + kv1 + sc + 32);
    }

    // S^T = K Q^T : A = K-frag (m=kv), B = Q-frag (n=q)
    f32x4 st[2][4] = {};   // [qf][kv-frag f]
#pragma unroll
    for (int c = 0; c < 2; c++) {
      bf16x8 bk[4];
#pragma unroll
      for (int f = 0; f < 4; f++)
        bk[f] = *(const bf16x8*)&Kls[p][(f * 16 + l16) * 72 + c * 32 + quad * 8];
#pragma unroll
      for (int qf = 0; qf < 2; qf++)
#pragma unroll
        for (int f = 0; f < 4; f++)
          st[qf][f] = __builtin_amdgcn_mfma_f32_16x16x32_bf16(bk[f], aq[qf][c], st[qf][f], 0, 0, 0);
    }

    // p~ = 2^s, packed f16; accumulate row sums; feed PV directly from regs
#pragma unroll
    for (int qf = 0; qf < 2; qf++) {
      union PK { hf16x2 r; f16x2 v; __half2 h; };
      PK e01[4], e23[4];
      __half2 it2 = __half2{__half(0.f), __half(0.f)};
#pragma unroll
      for (int f = 0; f < 4; f++) {
        PK a01, a23;
        a01.r = __builtin_amdgcn_cvt_pkrtz(st[qf][f][0], st[qf][f][1]);
        a23.r = __builtin_amdgcn_cvt_pkrtz(st[qf][f][2], st[qf][f][3]);
        e01[f].h = h2exp2(a01.h);
        e23[f].h = h2exp2(a23.h);
        it2 = __hadd2(it2, __hadd2(e01[f].h, e23[f].h));
      }
      psum[qf] += __low2float(it2) + __high2float(it2);
      // O^T += V^T P^T : A = V^T-frag (from LDS), B = P^T frag (from regs)
#pragma unroll
      for (int f = 0; f < 4; f++) {
        union { f16x4 v; f16x2 h[2]; } pb;
        pb.h[0] = e01[f].v;
        pb.h[1] = e23[f].v;
#pragma unroll
        for (int g = 0; g < 4; g++) {
          f16x4 va = *(const f16x4*)&Vls[p][(g * 16 + l16) * 72 + f * 16 + quad * 4];
          Oacc[qf][g] = __builtin_amdgcn_mfma_f32_16x16x16f16(va, pb.v, Oacc[qf][g], 0, 0, 0);
        }
      }
    }
  }

  // psum: lanes with same l16 across the 4 quads hold disjoint kv subsets
  float inv[2];
#pragma unroll
  for (int qf = 0; qf < 2; qf++) {
    float v = psum[qf];
    v += __shfl_xor(v, 16);
    v += __shfl_xor(v, 32);
    inv[qf] = 1.f / v;
  }

  // epilogue: O^T (col=q, row=dh) -> LDS transpose -> coalesced row-major store
  __syncthreads();
  u16* Ols = (u16*)Kls;  // 128 rows x 72 pitch = 9216 u16 (fits in Kls)
#pragma unroll
  for (int qf = 0; qf < 2; qf++)
#pragma unroll
    for (int g = 0; g < 4; g++) {
      u16x4 o;
#pragma unroll
      for (int r = 0; r < 4; r++) o[r] = f2bf(Oacc[qf][g][r] * inv[qf]);
      *(u16x4*)&Ols[(wave * 32 + qf * 16 + l16) * 72 + g * 16 + quad * 4] = o;
    }
  __syncthreads();
  const int row = t >> 1, half = t & 1;
  u16* gO = Ob + (size_t)(b * 2048 + q0 + row) * 1024 + h * 64 + half * 32;
#pragma unroll
  for (int j = 0; j < 4; j++)
    *(u16x8*)(gO + j * 8) = *(const u16x8*)&Ols[row * 72 + half * 32 + j * 8];
}

// ---------------- LayerNorm ----------------

__global__ __launch_bounds__(256) void k_ln(const float* __restrict__ y,
                                            const float* __restrict__ g,
                                            const float* __restrict__ bt,
                                            float* __restrict__ out) {
  const int row = blockIdx.x;
  const int t = threadIdx.x;
  float4 v = *(const float4*)(y + row * 1024 + t * 4);
  float s1 = v.x + v.y + v.z + v.w;
  float s2 = v.x * v.x + v.y * v.y + v.z * v.z + v.w * v.w;
#pragma unroll
  for (int off = 32; off; off >>= 1) {
    s1 += __shfl_down(s1, off);
    s2 += __shfl_down(s2, off);
  }
  __shared__ float red[10];
  const int wave = t >> 6, lane = t & 63;
  if (lane == 0) { red[wave] = s1; red[4 + wave] = s2; }
  __syncthreads();
  if (t == 0) {
    float a = red[0] + red[1] + red[2] + red[3];
    float bsum = red[4] + red[5] + red[6] + red[7];
    float mean = a * (1.f / 1024.f);
    float var = bsum * (1.f / 1024.f) - mean * mean;
    red[8] = mean;
    red[9] = rsqrtf(var + 1e-6f);
  }
  __syncthreads();
  float mean = red[8], iv = red[9];
  float4 gv = *(const float4*)(g + t * 4);
  float4 bv = *(const float4*)(bt + t * 4);
  float4 o;
  o.x = (v.x - mean) * iv * gv.x + bv.x;
  o.y = (v.y - mean) * iv * gv.y + bv.y;
  o.z = (v.z - mean) * iv * gv.z + bv.z;
  o.w = (v.w - mean) * iv * gv.w + bv.w;
  *(float4*)(out + row * 1024 + t * 4) = o;
}

// ---------------- launch ----------------

extern "C" void kernel_launch(void* const* d_in, const int* in_sizes, int n_in,
                              void* d_out, int out_size, void* d_ws, size_t ws_size,
                              hipStream_t stream) {
  const float* x  = (const float*)d_in[0];
  const float* wq = (const float*)d_in[1];
  const float* wk = (const float*)d_in[2];
  const float* wv = (const float*)d_in[3];
  const float* wp = (const float*)d_in[4];
  const float* bp = (const float*)d_in[5];
  const float* g  = (const float*)d_in[6];
  const float* bt = (const float*)d_in[7];
  float* out = (float*)d_out;
  char* ws = (char*)d_ws;

  u16* xbf = (u16*)(ws);
  u16* wqT = (u16*)(ws + (16 << 20));        // [3072][1024] fused: wq|wk|wv
  u16* wkT = wqT + (size_t)1024 * 1024;
  u16* wvT = wqT + (size_t)2048 * 1024;
  u16* wpT = (u16*)(ws + (22 << 20));
  u16* Qb  = (u16*)(ws + (24 << 20));
  u16* Kb  = (u16*)(ws + (40 << 20));
  u16* VbT = (u16*)(ws + (56 << 20));
  u16* Ob  = (u16*)(ws);                   // aliases xbf (dead after QKV GEMM)
  float* ypre = (float*)(ws + (24 << 20)); // aliases Q,K (dead after attention)

  k_convx<<<4096, 256, 0, stream>>>(x, xbf);
  k_convwT<<<dim3(16, 16, 4), 256, 0, stream>>>(wq, wk, wv, wp, wqT, wkT, wvT, wpT);
  k_gemm_qkv<<<dim3(64, 24), 256, 0, stream>>>(xbf, wqT, Qb, Kb, VbT);
  k_attn<<<dim3(16, 64), 256, 0, stream>>>(Qb, Kb, VbT, Ob);
  k_gemm_proj<<<dim3(64, 8), 256, 0, stream>>>(Ob, wpT, x, bp, ypre);
  k_ln<<<8192, 256, 0, stream>>>(ypre, g, bt, out);
}

// Round 8
// 274.475 us; speedup vs baseline: 1.6742x; 1.1116x over previous
//
#include <hip/hip_runtime.h>
#include <hip/hip_fp16.h>

// Fused MHA block: y = LN(x + b_proj + softmax(QK^T/8) V W_proj), MFMA compute.
// B=4, S=2048, D=1024, H=16, Dh=64.  M = B*S = 8192.
//
// Workspace layout (needs ~72 MB; aliased):
//   [0,16M)   x_bf16 [8192][1024]     -- later reused as O bf16 [8192][1024]
//   [16,22M)  wqkvT bf16 [3072n][1024k]  (wq/wk/wv transposed, contiguous)
//   [22,24M)  wprojT bf16 [1024n][1024k]
//   [24,40M)  Q bf16 [8192][1024]  (PRE-SCALED by 0.125*log2e; n = h*64+dh)
//   [40,56M)  K bf16
//   [56,72M)  V^T f16 [b][h][dh][s]   (written transposed+f16 by QKV GEMM epilogue)
//   [24,40M)  y_pre bf16 [8192][1024]  (aliases Q after attention)

typedef unsigned short u16;
typedef __attribute__((ext_vector_type(8))) u16 u16x8;
typedef __attribute__((ext_vector_type(4))) u16 u16x4;
typedef __attribute__((ext_vector_type(8))) __bf16 bf16x8;
typedef __attribute__((ext_vector_type(4))) _Float16 f16x4;
typedef __attribute__((ext_vector_type(2))) _Float16 f16x2;
typedef __attribute__((ext_vector_type(2))) __fp16 hf16x2;   // cvt_pkrtz return type
typedef __attribute__((ext_vector_type(4))) float f32x4;

// Q is pre-scaled by SM_C1 so scores come out of the MFMA in log2 units:
// p~ = 2^(s_scaled) = exp(s_raw/8).  The softmax offset/scale cancels in
// O = sum(p~ v)/sum(p~), so NO fma and NO offset in the inner loop.
#define SM_C1 0.1803368801111204f   /* 0.125 * log2(e) */

static __device__ __forceinline__ u16 f2bf(float f) {
  union { float f; unsigned int u; } v; v.f = f;
  unsigned int u = v.u;
  return (u16)((u + 0x7fffu + ((u >> 16) & 1u)) >> 16);  // RNE
}
static __device__ __forceinline__ float bf2f(u16 b) {
  union { unsigned int u; float f; } v; v.u = ((unsigned int)b) << 16;
  return v.f;
}
static __device__ __forceinline__ u16 f2h(float f) {
  union { _Float16 h; u16 u; } v; v.h = (_Float16)f;  // v_cvt_f16_f32, RNE
  return v.u;
}

// async global->LDS, 16B per lane; LDS dest = wave-uniform base + lane*16
static __device__ __forceinline__ void gld16(const u16* g, u16* l) {
  __builtin_amdgcn_global_load_lds((const __attribute__((address_space(1))) void*)g,
                                   (__attribute__((address_space(3))) void*)l, 16, 0, 0);
}

// ---------------- conversion kernels ----------------

__global__ __launch_bounds__(256) void k_convx(const float* __restrict__ x,
                                               u16* __restrict__ xbf) {
  int i = (blockIdx.x * 256 + threadIdx.x) * 8;
  float4 a = *(const float4*)(x + i);
  float4 b = *(const float4*)(x + i + 4);
  u16x8 o;
  o[0] = f2bf(a.x); o[1] = f2bf(a.y); o[2] = f2bf(a.z); o[3] = f2bf(a.w);
  o[4] = f2bf(b.x); o[5] = f2bf(b.y); o[6] = f2bf(b.z); o[7] = f2bf(b.w);
  *(u16x8*)(xbf + i) = o;
}

// transpose 1024x1024 fp32 -> bf16 [n][k], LDS tiled, both sides coalesced
__global__ __launch_bounds__(256) void k_convwT(const float* __restrict__ w0,
                                                const float* __restrict__ w1,
                                                const float* __restrict__ w2,
                                                const float* __restrict__ w3,
                                                u16* __restrict__ o0, u16* __restrict__ o1,
                                                u16* __restrict__ o2, u16* __restrict__ o3) {
  __shared__ float tile[64][65];
  const float* w = blockIdx.z == 0 ? w0 : blockIdx.z == 1 ? w1 : blockIdx.z == 2 ? w2 : w3;
  u16* o = blockIdx.z == 0 ? o0 : blockIdx.z == 1 ? o1 : blockIdx.z == 2 ? o2 : o3;
  const int k0 = blockIdx.x * 64, n0 = blockIdx.y * 64;
  const int t = threadIdx.x;
#pragma unroll
  for (int i = 0; i < 16; i++) {
    int idx = t + 256 * i;
    int k = idx >> 6, n = idx & 63;
    tile[k][n] = w[(k0 + k) * 1024 + n0 + n];
  }
  __syncthreads();
#pragma unroll
  for (int i = 0; i < 16; i++) {
    int idx = t + 256 * i;
    int n = idx >> 6, k = idx & 63;
    o[(n0 + n) * 1024 + k0 + k] = f2bf(tile[k][n]);
  }
}

// ---------------- QKV GEMM (m97 structure) ----------------
// 128x128 tile, BK=64, 4 waves as 2x2, 4x4 16x16x32 frags/wave.
// Staging via global_load_lds dwordx4; XOR-swizzled granules (kg = pg ^ (row&7))
// so ds_read_b128 fragment reads are bank-conflict-free without padding.
// wT is the fused [3072][1024] (wq|wk|wv transposed). sel: 0 -> Q bf16*SM_C1;
// 1 -> K bf16 row-major; 2 -> V^T f16 [b][h][dh][s].

__global__ __launch_bounds__(256) void k_gemm_qkv(const u16* __restrict__ xbf,
                                                  const u16* __restrict__ wT,
                                                  u16* __restrict__ Qb, u16* __restrict__ Kb,
                                                  u16* __restrict__ VbT) {
  __shared__ alignas(16) u16 Als[128 * 64];
  __shared__ alignas(16) u16 Bls[128 * 64];
  const int t = threadIdx.x;
  const int wv = t >> 6, lane = t & 63, quad = lane >> 4, l16 = lane & 15;
  const int wm = wv >> 1, wn = wv & 1;
  const int m0 = blockIdx.x * 128;
  const int nt = blockIdx.y;                 // 0..23
  const int row = t >> 3;                    // staging row 0..31 (+32 per issue)
  const int kg = (t & 7) ^ (row & 7);        // swizzled k-granule
  const u16* aG = xbf + (size_t)(m0 + row) * 1024 + kg * 8;
  const u16* bG = wT + (size_t)(nt * 128 + row) * 1024 + kg * 8;
  const int sw = l16 & 7;
  const int aA0 = (wm * 64 + l16) * 64 + ((quad) ^ sw) * 8;
  const int aA1 = (wm * 64 + l16) * 64 + ((4 + quad) ^ sw) * 8;
  const int bA0 = (wn * 64 + l16) * 64 + ((quad) ^ sw) * 8;
  const int bA1 = (wn * 64 + l16) * 64 + ((4 + quad) ^ sw) * 8;

  f32x4 acc[4][4] = {};
  for (int k0 = 0; k0 < 1024; k0 += 64) {
    __syncthreads();
#pragma unroll
    for (int i = 0; i < 4; i++) {
      gld16(aG + i * 32 * 1024 + k0, &Als[(i * 256 + wv * 64) * 8]);
      gld16(bG + i * 32 * 1024 + k0, &Bls[(i * 256 + wv * 64) * 8]);
    }
    __syncthreads();
#pragma unroll
    for (int c = 0; c < 2; c++) {
      bf16x8 a[4], b[4];
#pragma unroll
      for (int f = 0; f < 4; f++) a[f] = *(const bf16x8*)&Als[(c ? aA1 : aA0) + f * 1024];
#pragma unroll
      for (int g = 0; g < 4; g++) b[g] = *(const bf16x8*)&Bls[(c ? bA1 : bA0) + g * 1024];
#pragma unroll
      for (int f = 0; f < 4; f++)
#pragma unroll
        for (int g = 0; g < 4; g++)
          acc[f][g] = __builtin_amdgcn_mfma_f32_16x16x32_bf16(a[f], b[g], acc[f][g], 0, 0, 0);
    }
  }

  const int sel = nt >> 3;
  const int n0 = (nt & 7) * 128 + wn * 64;
  const int mBase = m0 + wm * 64 + quad * 4;
  if (sel < 2) {
    u16* Ob = sel == 0 ? Qb : Kb;
    const float scl = sel == 0 ? SM_C1 : 1.0f;
#pragma unroll
    for (int f = 0; f < 4; f++)
#pragma unroll
      for (int g = 0; g < 4; g++)
#pragma unroll
        for (int r = 0; r < 4; r++) {
          int m = mBase + f * 16 + r;
          int n = n0 + g * 16 + l16;
          Ob[(size_t)m * 1024 + n] = f2bf(acc[f][g][r] * scl);
        }
  } else {
    // V^T f16: [b][h][dh][s]; 4 r-values are 4 consecutive s -> one 8B store
#pragma unroll
    for (int f = 0; f < 4; f++) {
      int m = mBase + f * 16;
      int bb = m >> 11, s = m & 2047;
#pragma unroll
      for (int g = 0; g < 4; g++) {
        int n = n0 + g * 16 + l16;
        int hh = n >> 6, dh = n & 63;
        u16x4 o;
#pragma unroll
        for (int r = 0; r < 4; r++) o[r] = f2h(acc[f][g][r]);
        *(u16x4*)&VbT[(size_t)(((bb << 4) + hh) * 64 + dh) * 2048 + s] = o;
      }
    }
  }
}

// ---------------- proj GEMM + bias + residual (same m97 structure) ----------------
// epilogue writes y_pre as bf16 (halves ypre HBM traffic; LN reads bf16)

__global__ __launch_bounds__(256) void k_gemm_proj(const u16* __restrict__ Abf,
                                                   const u16* __restrict__ wT,
                                                   const float* __restrict__ x,
                                                   const float* __restrict__ bias,
                                                   u16* __restrict__ ypre) {
  __shared__ alignas(16) u16 Als[128 * 64];
  __shared__ alignas(16) u16 Bls[128 * 64];
  const int t = threadIdx.x;
  const int wv = t >> 6, lane = t & 63, quad = lane >> 4, l16 = lane & 15;
  const int wm = wv >> 1, wn = wv & 1;
  const int m0 = blockIdx.x * 128;
  const int n0t = blockIdx.y * 128;
  const int row = t >> 3;
  const int kg = (t & 7) ^ (row & 7);
  const u16* aG = Abf + (size_t)(m0 + row) * 1024 + kg * 8;
  const u16* bG = wT + (size_t)(n0t + row) * 1024 + kg * 8;
  const int sw = l16 & 7;
  const int aA0 = (wm * 64 + l16) * 64 + ((quad) ^ sw) * 8;
  const int aA1 = (wm * 64 + l16) * 64 + ((4 + quad) ^ sw) * 8;
  const int bA0 = (wn * 64 + l16) * 64 + ((quad) ^ sw) * 8;
  const int bA1 = (wn * 64 + l16) * 64 + ((4 + quad) ^ sw) * 8;

  f32x4 acc[4][4] = {};
  for (int k0 = 0; k0 < 1024; k0 += 64) {
    __syncthreads();
#pragma unroll
    for (int i = 0; i < 4; i++) {
      gld16(aG + i * 32 * 1024 + k0, &Als[(i * 256 + wv * 64) * 8]);
      gld16(bG + i * 32 * 1024 + k0, &Bls[(i * 256 + wv * 64) * 8]);
    }
    __syncthreads();
#pragma unroll
    for (int c = 0; c < 2; c++) {
      bf16x8 a[4], b[4];
#pragma unroll
      for (int f = 0; f < 4; f++) a[f] = *(const bf16x8*)&Als[(c ? aA1 : aA0) + f * 1024];
#pragma unroll
      for (int g = 0; g < 4; g++) b[g] = *(const bf16x8*)&Bls[(c ? bA1 : bA0) + g * 1024];
#pragma unroll
      for (int f = 0; f < 4; f++)
#pragma unroll
        for (int g = 0; g < 4; g++)
          acc[f][g] = __builtin_amdgcn_mfma_f32_16x16x32_bf16(a[f], b[g], acc[f][g], 0, 0, 0);
    }
  }

  const int n0 = n0t + wn * 64;
  const int mBase = m0 + wm * 64 + quad * 4;
#pragma unroll
  for (int g = 0; g < 4; g++) {
    int n = n0 + g * 16 + l16;
    float bn = bias[n];
#pragma unroll
    for (int f = 0; f < 4; f++)
#pragma unroll
      for (int r = 0; r < 4; r++) {
        int m = mBase + f * 16 + r;
        ypre[(size_t)m * 1024 + n] = f2bf(acc[f][g][r] + bn + x[(size_t)m * 1024 + n]);
      }
  }
}

// ---------------- flash attention (transposed-score form, 256-q blocks) ----------------
// grid (S/256, B*H); block 256 = 4 waves; wave handles 64 q (4 q-frags).
// S^T = K Q_scaled^T via 16x16x32 bf16 MFMA (C-layout: col=q, row=kv).
// p~ = 2^s via packed-f16 exp; P^T (C-layout) == B-operand of 16x16x16 f16
// MFMA -> PV feeds straight from registers.  K and V^T staged in LDS
// (double-buffered, 1 barrier/iter).  qf=4 halves per-q K ds_reads, staging
// traffic, and barrier count vs qf=2.

__global__ __launch_bounds__(256, 2) void k_attn(const u16* __restrict__ Qb,
                                                 const u16* __restrict__ Kb,
                                                 const u16* __restrict__ VbT,
                                                 u16* __restrict__ Ob) {
  // [0..1]: K ping/pong [kv][dh] bf16 pitch 72; [2..3]: V ping/pong [dh][kv] f16
  __shared__ alignas(16) u16 smem[4][64 * 72];
  const int b = blockIdx.y >> 4, h = blockIdx.y & 15;
  const int q0 = blockIdx.x * 256;
  const int t = threadIdx.x;
  const int wave = t >> 6, lane = t & 63, quad = lane >> 4, l16 = lane & 15;
  const int sr = t >> 2, sc = (t & 3) * 8;

  // Q fragments (pre-scaled)
  bf16x8 aq[4][2];
#pragma unroll
  for (int qf = 0; qf < 4; qf++)
#pragma unroll
    for (int c = 0; c < 2; c++)
      aq[qf][c] = *(const bf16x8*)&Qb[(size_t)(b * 2048 + q0 + wave * 64 + qf * 16 + l16) * 1024 +
                                      h * 64 + c * 32 + quad * 8];

  f32x4 Oacc[4][4] = {};   // [qf][dh-frag g]; C-layout col=q, row=dh_local
  float psum[4] = {};      // per-lane partial row sum for q=l16 (per qf)

  const u16* kBase = Kb + (size_t)(b * 2048) * 1024 + h * 64;
  const u16* vtRow = VbT + (size_t)((b * 16 + h) * 64 + sr) * 2048;

  u16x8 rk0, rk1, rv0, rv1;
  {
    const u16* kR = kBase + (size_t)sr * 1024;
    rk0 = *(const u16x8*)(kR + sc);
    rk1 = *(const u16x8*)(kR + sc + 32);
    rv0 = *(const u16x8*)(vtRow + sc);
    rv1 = *(const u16x8*)(vtRow + sc + 32);
  }

  for (int kt = 0; kt < 32; kt++) {
    const int p = kt & 1;
    u16* Kls = smem[p];
    u16* Vls = smem[2 + p];
    // stage regs -> LDS[p]
    *(u16x8*)&Kls[sr * 72 + sc]      = rk0;
    *(u16x8*)&Kls[sr * 72 + sc + 32] = rk1;
    *(u16x8*)&Vls[sr * 72 + sc]      = rv0;
    *(u16x8*)&Vls[sr * 72 + sc + 32] = rv1;
    __syncthreads();
    // prefetch kt+1 (consumed at next iter's write; hidden under compute)
    if (kt < 31) {
      const int kv1 = (kt + 1) * 64;
      const u16* kR = kBase + (size_t)(kv1 + sr) * 1024;
      rk0 = *(const u16x8*)(kR + sc);
      rk1 = *(const u16x8*)(kR + sc + 32);
      rv0 = *(const u16x8*)(vtRow + kv1 + sc);
      rv1 = *(const u16x8*)(vtRow + kv1 + sc + 32);
    }

    // S^T = K Q^T : A = K-frag (m=kv), B = Q-frag (n=q)
    f32x4 st[4][4];   // [qf][kv-frag f]
#pragma unroll
    for (int qf = 0; qf < 4; qf++)
#pragma unroll
      for (int f = 0; f < 4; f++) st[qf][f] = f32x4{0.f, 0.f, 0.f, 0.f};
#pragma unroll
    for (int c = 0; c < 2; c++) {
      bf16x8 bk[4];
#pragma unroll
      for (int f = 0; f < 4; f++)
        bk[f] = *(const bf16x8*)&Kls[(f * 16 + l16) * 72 + c * 32 + quad * 8];
#pragma unroll
      for (int qf = 0; qf < 4; qf++)
#pragma unroll
        for (int f = 0; f < 4; f++)
          st[qf][f] = __builtin_amdgcn_mfma_f32_16x16x32_bf16(bk[f], aq[qf][c], st[qf][f], 0, 0, 0);
    }

    // V A-operand frags from LDS, shared by all qf
    f16x4 va[4][4];  // [f=kv16-frag][g=dh-frag]
#pragma unroll
    for (int f = 0; f < 4; f++)
#pragma unroll
      for (int g = 0; g < 4; g++)
        va[f][g] = *(const f16x4*)&Vls[(g * 16 + l16) * 72 + f * 16 + quad * 4];

    // p~ = 2^s, packed f16; accumulate row sums; feed PV directly from regs
#pragma unroll
    for (int qf = 0; qf < 4; qf++) {
      union PK { hf16x2 r; f16x2 v; __half2 h; };
      PK e01[4], e23[4];
      __half2 it2 = __half2{__half(0.f), __half(0.f)};
#pragma unroll
      for (int f = 0; f < 4; f++) {
        PK a01, a23;
        a01.r = __builtin_amdgcn_cvt_pkrtz(st[qf][f][0], st[qf][f][1]);
        a23.r = __builtin_amdgcn_cvt_pkrtz(st[qf][f][2], st[qf][f][3]);
        e01[f].h = h2exp2(a01.h);
        e23[f].h = h2exp2(a23.h);
        it2 = __hadd2(it2, __hadd2(e01[f].h, e23[f].h));
      }
      psum[qf] += __low2float(it2) + __high2float(it2);
      // O^T += V^T P^T : A = V^T-frag, B = P^T frag (from regs)
#pragma unroll
      for (int f = 0; f < 4; f++) {
        union { f16x4 v; f16x2 h[2]; } pb;
        pb.h[0] = e01[f].v;
        pb.h[1] = e23[f].v;
#pragma unroll
        for (int g = 0; g < 4; g++)
          Oacc[qf][g] = __builtin_amdgcn_mfma_f32_16x16x16f16(va[f][g], pb.v, Oacc[qf][g], 0, 0, 0);
      }
    }
  }

  // psum: lanes with same l16 across the 4 quads hold disjoint kv subsets
  float inv[4];
#pragma unroll
  for (int qf = 0; qf < 4; qf++) {
    float v = psum[qf];
    v += __shfl_xor(v, 16);
    v += __shfl_xor(v, 32);
    inv[qf] = 1.f / v;
  }

  // epilogue: O^T (col=q, row=dh) -> LDS transpose -> coalesced row-major store
  __syncthreads();
  u16* Ols = (u16*)smem;  // 256 rows x 72 pitch = 18432 u16 (fits exactly)
#pragma unroll
  for (int qf = 0; qf < 4; qf++)
#pragma unroll
    for (int g = 0; g < 4; g++) {
      u16x4 o;
#pragma unroll
      for (int r = 0; r < 4; r++) o[r] = f2bf(Oacc[qf][g][r] * inv[qf]);
      *(u16x4*)&Ols[(wave * 64 + qf * 16 + l16) * 72 + g * 16 + quad * 4] = o;
    }
  __syncthreads();
  u16* gO = Ob + (size_t)(b * 2048 + q0 + t) * 1024 + h * 64;
#pragma unroll
  for (int j = 0; j < 8; j++)
    *(u16x8*)(gO + j * 8) = *(const u16x8*)&Ols[t * 72 + j * 8];
}

// ---------------- LayerNorm (bf16 input, fp32 output) ----------------

__global__ __launch_bounds__(256) void k_ln(const u16* __restrict__ y,
                                            const float* __restrict__ g,
                                            const float* __restrict__ bt,
                                            float* __restrict__ out) {
  const int row = blockIdx.x;
  const int t = threadIdx.x;
  u16x4 rv = *(const u16x4*)(y + row * 1024 + t * 4);
  float vx = bf2f(rv[0]), vy = bf2f(rv[1]), vz = bf2f(rv[2]), vw = bf2f(rv[3]);
  float s1 = vx + vy + vz + vw;
  float s2 = vx * vx + vy * vy + vz * vz + vw * vw;
#pragma unroll
  for (int off = 32; off; off >>= 1) {
    s1 += __shfl_down(s1, off);
    s2 += __shfl_down(s2, off);
  }
  __shared__ float red[10];
  const int wave = t >> 6, lane = t & 63;
  if (lane == 0) { red[wave] = s1; red[4 + wave] = s2; }
  __syncthreads();
  if (t == 0) {
    float a = red[0] + red[1] + red[2] + red[3];
    float bsum = red[4] + red[5] + red[6] + red[7];
    float mean = a * (1.f / 1024.f);
    float var = bsum * (1.f / 1024.f) - mean * mean;
    red[8] = mean;
    red[9] = rsqrtf(var + 1e-6f);
  }
  __syncthreads();
  float mean = red[8], iv = red[9];
  float4 gv = *(const float4*)(g + t * 4);
  float4 bv = *(const float4*)(bt + t * 4);
  float4 o;
  o.x = (vx - mean) * iv * gv.x + bv.x;
  o.y = (vy - mean) * iv * gv.y + bv.y;
  o.z = (vz - mean) * iv * gv.z + bv.z;
  o.w = (vw - mean) * iv * gv.w + bv.w;
  *(float4*)(out + row * 1024 + t * 4) = o;
}

// ---------------- launch ----------------

extern "C" void kernel_launch(void* const* d_in, const int* in_sizes, int n_in,
                              void* d_out, int out_size, void* d_ws, size_t ws_size,
                              hipStream_t stream) {
  const float* x  = (const float*)d_in[0];
  const float* wq = (const float*)d_in[1];
  const float* wk = (const float*)d_in[2];
  const float* wv = (const float*)d_in[3];
  const float* wp = (const float*)d_in[4];
  const float* bp = (const float*)d_in[5];
  const float* g  = (const float*)d_in[6];
  const float* bt = (const float*)d_in[7];
  float* out = (float*)d_out;
  char* ws = (char*)d_ws;

  u16* xbf = (u16*)(ws);
  u16* wqT = (u16*)(ws + (16 << 20));        // [3072][1024] fused: wq|wk|wv
  u16* wkT = wqT + (size_t)1024 * 1024;
  u16* wvT = wqT + (size_t)2048 * 1024;
  u16* wpT = (u16*)(ws + (22 << 20));
  u16* Qb  = (u16*)(ws + (24 << 20));
  u16* Kb  = (u16*)(ws + (40 << 20));
  u16* VbT = (u16*)(ws + (56 << 20));
  u16* Ob  = (u16*)(ws);                   // aliases xbf (dead after QKV GEMM)
  u16* ypre = (u16*)(ws + (24 << 20));     // bf16, aliases Qb (dead after attention)

  k_convx<<<4096, 256, 0, stream>>>(x, xbf);
  k_convwT<<<dim3(16, 16, 4), 256, 0, stream>>>(wq, wk, wv, wp, wqT, wkT, wvT, wpT);
  k_gemm_qkv<<<dim3(64, 24), 256, 0, stream>>>(xbf, wqT, Qb, Kb, VbT);
  k_attn<<<dim3(8, 64), 256, 0, stream>>>(Qb, Kb, VbT, Ob);
  k_gemm_proj<<<dim3(64, 8), 256, 0, stream>>>(Ob, wpT, x, bp, ypre);
  k_ln<<<8192, 256, 0, stream>>>(ypre, g, bt, out);
}